// Round 5
// baseline (219.321 us; speedup 1.0000x reference)
//
#include <hip/hip_runtime.h>
#include <hip/hip_bf16.h>

// B=4, S=1024, D=1024, H=16, HD=64 — tokens M=4096, feature K=1024
// fp32 inputs -> bf16 convert pass -> all GEMMs/attention in bf16 MFMA
// (fp32 accumulate) -> fp32 output.
// ROUND 5: gemm8p K-loop -> register-double-buffered single-barrier
// pipeline. R4 measured 2875 cy/K-tile vs ~1920 LDS-port floor: the
// 2-phase structure phase-locked waves (all read, then all MFMA). New:
// per K-tile {vmcnt(6)+lgkm(0); barrier; STAGE(t+3); READ(t+1)->regs';
// MFMA32(t)} — ds_reads overlap the MFMA cluster, 1 barrier/K-tile,
// 3-buffer ring (stage dist 3, flight 2 tiles). Hazards: WAR on LDS
// certified by pre-barrier lgkm(0) of every wave; RAW by pre-barrier
// vmcnt(6). Reg sets statically named (rule 20), nkt always even.
// attn / oproj / cvt unchanged from round 4.

typedef __bf16 bf16x8 __attribute__((ext_vector_type(8)));
typedef __bf16 bf16x4 __attribute__((ext_vector_type(4)));
typedef float  f32x4  __attribute__((ext_vector_type(4)));

#define DMODEL 1024

#define ASYNC_LOAD16(gp, lp)                                                  \
    __builtin_amdgcn_global_load_lds(                                         \
        (const __attribute__((address_space(1))) unsigned int*)(gp),          \
        (__attribute__((address_space(3))) unsigned int*)(lp), 16, 0, 0)

// ---------------------------------------------------------------------------
// fp32 -> bf16 conversion: x (4M) + 6 weights (1M each); Wbar pre-scaled by
// 0.2 and Wbeat by 0.1 (folds the score-bias scales into the GEMM).
// ---------------------------------------------------------------------------
__global__ __launch_bounds__(256) void cvt_kernel(
    const float* __restrict__ x,
    const float* __restrict__ Wq, const float* __restrict__ Wk,
    const float* __restrict__ Wv, const float* __restrict__ Wbar,
    const float* __restrict__ Wbeat, const float* __restrict__ Wo,
    __bf16* __restrict__ dst)
{
    const int g = blockIdx.x * 256 + threadIdx.x;
    const size_t e = (size_t)g * 8;
    const int seg = (int)(e >> 20);
    const float* src; size_t off; float s = 1.0f;
    if (seg < 4)       { src = x;     off = e; }
    else if (seg == 4) { src = Wq;    off = e - ((size_t)4 << 20); }
    else if (seg == 5) { src = Wk;    off = e - ((size_t)5 << 20); }
    else if (seg == 6) { src = Wv;    off = e - ((size_t)6 << 20); }
    else if (seg == 7) { src = Wbar;  off = e - ((size_t)7 << 20); s = 0.2f; }
    else if (seg == 8) { src = Wbeat; off = e - ((size_t)8 << 20); s = 0.1f; }
    else               { src = Wo;    off = e - ((size_t)9 << 20); }
    const float4 a = *(const float4*)&src[off];
    const float4 b = *(const float4*)&src[off + 4];
    bf16x8 v;
    v[0] = (__bf16)(a.x * s); v[1] = (__bf16)(a.y * s);
    v[2] = (__bf16)(a.z * s); v[3] = (__bf16)(a.w * s);
    v[4] = (__bf16)(b.x * s); v[5] = (__bf16)(b.y * s);
    v[6] = (__bf16)(b.z * s); v[7] = (__bf16)(b.w * s);
    *(bf16x8*)&dst[e] = v;
}

// ---------------------------------------------------------------------------
// reg-dbuf GEMM: BM=128, BN=256, BK=64, 512 threads = 8 waves (2M x 4N),
// wave tile 64x64 (acc 4x4). LDS: A 3x[128][64] + B 3x[256][64] = 144KB,
// T2 swizzle byte^=((row&7)<<4) on source + read (0 conflicts, verified).
// Body for tile t (read buf (t+1)%3, stage buf t%3):
//   s_waitcnt vmcnt(6) lgkmcnt(0); s_barrier;
//   STAGE(t+3); READ(t+1)->other reg set; 32 MFMA on current set.
// Tail: vmcnt(0) at t=nkt-2; skip stage/read when out of range.
// Block map: bid 0..127 keff (3 terms, ONE fp32 acc over 48 K-tiles),
// 128..255 q (bias + 0.125 scale), 256..383 v (transposed store).
// ---------------------------------------------------------------------------

#define SWZ_COL(r_, ks_) \
    (((((ks_) * 64) + quad * 16) ^ (((r_) & 7) << 4)) >> 1)

#define READ_SET(c_, AF_, BF_)                                                \
    do {                                                                      \
        _Pragma("unroll") for (int mh = 0; mh < 2; ++mh)                      \
        _Pragma("unroll") for (int mi = 0; mi < 2; ++mi) {                    \
            const int r_ = ((w >> 2) << 5) + mh * 64 + mi * 16 + l15;         \
            _Pragma("unroll") for (int ks = 0; ks < 2; ++ks)                  \
                AF_[mh][mi][ks] = *(const bf16x8*)&Alds[(c_) * 8192 +         \
                                        r_ * 64 + SWZ_COL(r_, ks)];           \
        }                                                                     \
        _Pragma("unroll") for (int nh = 0; nh < 2; ++nh)                      \
        _Pragma("unroll") for (int nj = 0; nj < 2; ++nj) {                    \
            const int r_ = ((w & 3) << 5) + nh * 128 + nj * 16 + l15;         \
            _Pragma("unroll") for (int ks = 0; ks < 2; ++ks)                  \
                BF_[nh][nj][ks] = *(const bf16x8*)&Blds[(c_) * 16384 +        \
                                        r_ * 64 + SWZ_COL(r_, ks)];           \
        }                                                                     \
    } while (0)

#define STAGE_A1(bufn_, h_, kt_)                                              \
    do {                                                                      \
        const int tm_ = (kt_) >> 4;                                           \
        const int k0_ = ((kt_) & 15) << 6;                                    \
        const __bf16* ap_ = (tm_ == 0) ? aA0##h_ : (tm_ == 1) ? aA1##h_       \
                                                              : aA2##h_;      \
        ASYNC_LOAD16(ap_ + k0_,                                               \
                     &Alds[(bufn_) * 8192 + (h_) * 4096 + w * 512]);          \
    } while (0)

#define STAGE_B2(bufn_, h_, kt_)                                              \
    do {                                                                      \
        const int tm_ = (kt_) >> 4;                                           \
        const int k0_ = ((kt_) & 15) << 6;                                    \
        const __bf16* wp_ = (tm_ == 0) ? W0 : (tm_ == 1) ? W1 : W2;           \
        ASYNC_LOAD16(wp_ + bro##h_##0 + k0_,                                  \
                     &Blds[(bufn_) * 16384 + (h_) * 8192 + w * 512]);         \
        ASYNC_LOAD16(wp_ + bro##h_##1 + k0_,                                  \
                     &Blds[(bufn_) * 16384 + (h_) * 8192 + 4096 + w * 512]);  \
    } while (0)

#define STAGE_TILE(bufn_, kt_)                                                \
    do {                                                                      \
        STAGE_A1(bufn_, 0, kt_); STAGE_A1(bufn_, 1, kt_);                     \
        STAGE_B2(bufn_, 0, kt_); STAGE_B2(bufn_, 1, kt_);                     \
    } while (0)

#define MFMA32_SET(AF_, BF_)                                                  \
    do {                                                                      \
        __builtin_amdgcn_s_setprio(1);                                        \
        _Pragma("unroll") for (int nh = 0; nh < 2; ++nh)                      \
        _Pragma("unroll") for (int mh = 0; mh < 2; ++mh)                      \
        _Pragma("unroll") for (int mi = 0; mi < 2; ++mi)                      \
        _Pragma("unroll") for (int nj = 0; nj < 2; ++nj)                      \
        _Pragma("unroll") for (int ks = 0; ks < 2; ++ks)                      \
            acc[mh * 2 + mi][nh * 2 + nj] =                                   \
                __builtin_amdgcn_mfma_f32_16x16x32_bf16(                      \
                    AF_[mh][mi][ks], BF_[nh][nj][ks],                         \
                    acc[mh * 2 + mi][nh * 2 + nj], 0, 0, 0);                  \
        __builtin_amdgcn_s_setprio(0);                                        \
    } while (0)

__global__ __launch_bounds__(512, 2) void gemm8p_kernel(
    const __bf16* __restrict__ xb,
    const __bf16* __restrict__ Wqb, const __bf16* __restrict__ Wkb,
    const __bf16* __restrict__ Wvb, const __bf16* __restrict__ Wbarb,
    const __bf16* __restrict__ Wbeatb,
    const float* __restrict__ bq, const float* __restrict__ bk,
    const float* __restrict__ bv, const float* __restrict__ bbar,
    const float* __restrict__ bbeat,
    const int* __restrict__ bar_idx, const int* __restrict__ beat_idx,
    __bf16* __restrict__ qbuf, __bf16* __restrict__ keffbuf,
    __bf16* __restrict__ vtbuf)
{
    __shared__ __align__(16) __bf16 Alds[3 * 8192];    // 3 buf x [128][64]
    __shared__ __align__(16) __bf16 Blds[3 * 16384];   // 3 buf x [256][64]

    const int bid = blockIdx.x;
    int mode, tk;
    if (bid < 128)      { mode = 1; tk = bid; }        // keff first (3x work)
    else if (bid < 256) { mode = 0; tk = bid - 128; }  // q
    else                { mode = 2; tk = bid - 256; }  // v
    const int m0 = (tk >> 2) << 7;                     // 32 m-tiles x 128
    const int n0 = (tk & 3) << 8;                      // 4 n-tiles x 256
    const int nkt = (mode == 1) ? 48 : 16;             // even, >= 4

    const int t    = (int)threadIdx.x;
    const int w    = t >> 6;
    const int lane = t & 63;
    const int l15  = lane & 15;
    const int quad = lane >> 4;

    // staging: thread t stages 16B at linear LDS byte t*16 within the
    // half-tile block => row = t>>3, slot = t&7. Source col carries the
    // involution swizzle: byte ^= ((row&7)<<4).
    const int srow = t >> 3;                                    // 0..63
    const int scol = ((((t & 7) * 16) ^ (((t >> 3) & 7) << 4)) >> 1);

    const __bf16* aA00 = xb + (size_t)(m0 + srow) * DMODEL + scol;
    const __bf16* aA01 = xb + (size_t)(m0 + 64 + srow) * DMODEL + scol;
    const __bf16* aA10 = aA00; const __bf16* aA11 = aA01;
    const __bf16* aA20 = aA00; const __bf16* aA21 = aA01;
    const __bf16 *W0, *W1, *W2;
    if (mode == 0)      { W0 = W1 = W2 = Wqb; }
    else if (mode == 2) { W0 = W1 = W2 = Wvb; }
    else {
        W0 = Wkb; W1 = Wbarb; W2 = Wbeatb;
        const int bb = m0 & ~1023;                 // batch base row
        const int lr = m0 & 1023;                  // seq-local tile base
        aA10 = xb + (size_t)(bb + bar_idx[lr + srow]) * DMODEL + scol;
        aA11 = xb + (size_t)(bb + bar_idx[lr + 64 + srow]) * DMODEL + scol;
        aA20 = xb + (size_t)(bb + beat_idx[lr + srow]) * DMODEL + scol;
        aA21 = xb + (size_t)(bb + beat_idx[lr + 64 + srow]) * DMODEL + scol;
    }
    const size_t bro00 = (size_t)(n0 + srow) * DMODEL + scol;
    const size_t bro01 = (size_t)(n0 + 64 + srow) * DMODEL + scol;
    const size_t bro10 = (size_t)(n0 + 128 + srow) * DMODEL + scol;
    const size_t bro11 = (size_t)(n0 + 192 + srow) * DMODEL + scol;

    f32x4 acc[4][4];
#pragma unroll
    for (int i = 0; i < 4; ++i)
#pragma unroll
        for (int j = 0; j < 4; ++j)
            acc[i][j] = {0.f, 0.f, 0.f, 0.f};
    bf16x8 afA[2][2][2], bfA[2][2][2];   // reg set A (even tiles)
    bf16x8 afB[2][2][2], bfB[2][2][2];   // reg set B (odd tiles)

    // prologue: stage tiles 0,1,2 (oldest-first for vmcnt semantics);
    // wait tile 0 (vmcnt(12)), publish, read tile 0 into set A.
    STAGE_TILE(0, 0);
    asm volatile("" ::: "memory");
    STAGE_TILE(1, 1);
    asm volatile("" ::: "memory");
    STAGE_TILE(2, 2);
    asm volatile("s_waitcnt vmcnt(12)" ::: "memory");
    __builtin_amdgcn_s_barrier();
    READ_SET(0, afA, bfA);

    int sb = 0, rb = 1;   // stage buf = tile%3, read buf = (tile+1)%3
#pragma unroll 1
    for (int kt = 0; kt < nkt; kt += 2) {
        // ---- body even: tile kt (regs in set A) ----
        if (kt + 2 < nkt)
            asm volatile("s_waitcnt vmcnt(6) lgkmcnt(0)" ::: "memory");
        else
            asm volatile("s_waitcnt vmcnt(0) lgkmcnt(0)" ::: "memory");
        __builtin_amdgcn_s_barrier();                 // publish tile kt+1
        if (kt + 3 < nkt) STAGE_TILE(sb, kt + 3);     // overwrite tile kt
        READ_SET(rb, afB, bfB);                       // tile kt+1 -> set B
        MFMA32_SET(afA, bfA);                         // tile kt
        sb = (sb == 2) ? 0 : sb + 1;
        rb = (rb == 2) ? 0 : rb + 1;

        // ---- body odd: tile kt+1 (regs in set B) ----
        if (kt + 3 < nkt)
            asm volatile("s_waitcnt vmcnt(6) lgkmcnt(0)" ::: "memory");
        else
            asm volatile("s_waitcnt vmcnt(0) lgkmcnt(0)" ::: "memory");
        __builtin_amdgcn_s_barrier();                 // publish tile kt+2
        if (kt + 4 < nkt) STAGE_TILE(sb, kt + 4);     // overwrite tile kt+1
        if (kt + 2 < nkt) READ_SET(rb, afA, bfA);     // tile kt+2 -> set A
        MFMA32_SET(afB, bfB);                         // tile kt+1
        sb = (sb == 2) ? 0 : sb + 1;
        rb = (rb == 2) ? 0 : rb + 1;
    }

    // epilogue: fp32 bias + store (same numerics/layouts as before)
#pragma unroll
    for (int an = 0; an < 4; ++an) {
        const int col = n0 + ((w & 3) << 5) + (an >> 1) * 128 +
                        (an & 1) * 16 + l15;
        float bias;
        if (mode == 0)      bias = bq[col];
        else if (mode == 1) bias = bk[col] + 0.2f * bbar[col] + 0.1f * bbeat[col];
        else                bias = bv[col];
#pragma unroll
        for (int am = 0; am < 4; ++am) {
            const int rowbase = m0 + ((w >> 2) << 5) + (am >> 1) * 64 +
                                (am & 1) * 16 + quad * 4;
            if (mode == 2) {
                const int bb = rowbase >> 10;
                const int sb2 = rowbase & 1023;
                bf16x4 vv;
#pragma unroll
                for (int r = 0; r < 4; ++r) vv[r] = (__bf16)(acc[am][an][r] + bias);
                *(bf16x4*)&vtbuf[((size_t)(bb * 1024 + col)) * 1024 + sb2] = vv;
            } else if (mode == 0) {
#pragma unroll
                for (int r = 0; r < 4; ++r)
                    qbuf[(size_t)(rowbase + r) * DMODEL + col] =
                        (__bf16)((acc[am][an][r] + bias) * 0.125f);  // attn scale
            } else {
#pragma unroll
                for (int r = 0; r < 4; ++r)
                    keffbuf[(size_t)(rowbase + r) * DMODEL + col] =
                        (__bf16)(acc[am][an][r] + bias);
            }
        }
    }
}

// ---------------------------------------------------------------------------
// out-proj: out = attn @ Wo^T + bo (fp32). 64x128 tile, grid 512 (2/CU).
// (unchanged from round 4)
// ---------------------------------------------------------------------------
__global__ __launch_bounds__(256) void oproj_kernel(
    const __bf16* __restrict__ attnb, const __bf16* __restrict__ Wob,
    const float* __restrict__ bo, float* __restrict__ outb)
{
    const int tile = blockIdx.x;          // 512 = 64 (m) x 8 (n)
    const int m0 = (tile >> 3) << 6;
    const int n0 = (tile & 7) << 7;

    __shared__ __align__(16) __bf16 Alds[64 * 32];
    __shared__ __align__(16) __bf16 Blds[128 * 32];

    const int t    = threadIdx.x;
    const int w    = t >> 6;
    const int lane = t & 63;
    const int l15  = lane & 15;
    const int quad = lane >> 4;
    const int wm   = (w >> 1) << 5;   // 2 m-waves x 2 n-waves
    const int wn   = (w & 1) << 6;
    const int srow = t >> 2;
    const int scol = ((((t & 3) * 16) ^ (((t >> 2) & 3) << 4)) >> 1);
    const int rcol = (((quad * 16) ^ ((l15 & 3) << 4)) >> 1);

    const __bf16* gA  = attnb + (size_t)(m0 + srow) * DMODEL + scol;
    const __bf16* gB0 = Wob + (size_t)(n0 + srow) * DMODEL + scol;
    const __bf16* gB1 = Wob + (size_t)(n0 + 64 + srow) * DMODEL + scol;
    __bf16* lA  = &Alds[w * 512];
    __bf16* lB0 = &Blds[w * 512];
    __bf16* lB1 = &Blds[2048 + w * 512];

    f32x4 acc[2][4];
    for (int i = 0; i < 2; ++i)
        for (int j = 0; j < 4; ++j)
            acc[i][j] = {0.f, 0.f, 0.f, 0.f};

    for (int kk = 0; kk < 32; ++kk) {
        const int k0 = kk * 32;
        ASYNC_LOAD16(gA + k0, lA);
        ASYNC_LOAD16(gB0 + k0, lB0);
        ASYNC_LOAD16(gB1 + k0, lB1);
        __syncthreads();

        bf16x8 af[2], bfr[4];
        for (int i = 0; i < 2; ++i)
            af[i] = *(const bf16x8*)&Alds[(wm + i * 16 + l15) * 32 + rcol];
        for (int j = 0; j < 4; ++j)
            bfr[j] = *(const bf16x8*)&Blds[(wn + j * 16 + l15) * 32 + rcol];

        for (int i = 0; i < 2; ++i)
            for (int j = 0; j < 4; ++j)
                acc[i][j] = __builtin_amdgcn_mfma_f32_16x16x32_bf16(
                    af[i], bfr[j], acc[i][j], 0, 0, 0);
        __syncthreads();
    }

    for (int j = 0; j < 4; ++j) {
        const int col = n0 + wn + j * 16 + l15;
        const float bias = bo[col];
        for (int i = 0; i < 2; ++i) {
            const int rowbase = m0 + wm + i * 16 + quad * 4;
            for (int r = 0; r < 4; ++r)
                outb[(size_t)(rowbase + r) * DMODEL + col] = acc[i][j][r] + bias;
        }
    }
}

// ---------------------------------------------------------------------------
// flash attention (unchanged from round 4): 512 blocks x 512 threads,
// QBLK=128, K/V 64-row tiles double-buffered via global_load_lds + T2
// swizzle, one-tile-ahead prefetch with counted vmcnt(2), complement
// qt-pairing. Shift-free softmax, ones-MFMA rowsum.
// ---------------------------------------------------------------------------
#define ATT_SLOT(q_, r_) ((((q_) ^ ((r_) & 7))) * 8)

__global__ __launch_bounds__(512) void attn_kernel(
    const __bf16* __restrict__ qbuf, const __bf16* __restrict__ keffbuf,
    const __bf16* __restrict__ vtbuf, __bf16* __restrict__ attnbuf)
{
    const int id = blockIdx.x;            // 512 = 64 bh x 8 qr
    const int bh = id & 63;
    const int b  = bh >> 4;
    const int h  = bh & 15;
    const int qr = id >> 6;
    const int qt = (qr < 4) ? qr : 11 - qr;   // complement pairing: 18 it/CU
    const int q0 = qt << 7;                   // 128 q-rows per block
    const int NT = 2 * qt + 2;                // causal K/V tiles of 64

    __shared__ __align__(16) __bf16 Klds[2][64 * 64];
    __shared__ __align__(16) __bf16 Vlds[2][64 * 64];
    __shared__ __align__(16) __bf16 Plds[8][16][72];

    const int t    = (int)threadIdx.x;
    const int w    = t >> 6;
    const int lane = t & 63;
    const int l15  = lane & 15;
    const int quad = lane >> 4;

    const int srow = t >> 3;                           // 0..63
    const int scol = ((t & 7) ^ (srow & 7)) * 8;       // elements, [0,64)

    const __bf16* gK = keffbuf + (size_t)(b * 1024 + srow) * DMODEL +
                       h * 64 + scol;                  // + j*64*DMODEL
    const __bf16* gV = vtbuf + (size_t)(b * 1024 + h * 64 + srow) * 1024 +
                       scol;                           // + j*64

    const __bf16* qbase =
        qbuf + (size_t)(b * 1024 + q0 + w * 16 + l15) * DMODEL + h * 64;
    bf16x8 qf0 = *(const bf16x8*)&qbase[quad * 8];
    bf16x8 qf1 = *(const bf16x8*)&qbase[32 + quad * 8];

    bf16x8 ones;
#pragma unroll
    for (int i = 0; i < 8; ++i) ones[i] = (__bf16)1.0f;

    f32x4 o[4];
#pragma unroll
    for (int i = 0; i < 4; ++i) o[i] = {0.f, 0.f, 0.f, 0.f};
    f32x4 lacc = {0.f, 0.f, 0.f, 0.f};

    ASYNC_LOAD16(gK, &Klds[0][t * 8]);
    ASYNC_LOAD16(gV, &Vlds[0][t * 8]);
    asm volatile("" ::: "memory");
    ASYNC_LOAD16(gK + (size_t)64 * DMODEL, &Klds[1][t * 8]);
    ASYNC_LOAD16(gV + 64, &Vlds[1][t * 8]);
    asm volatile("s_waitcnt vmcnt(2)" ::: "memory");
    __builtin_amdgcn_s_barrier();

#pragma unroll 1
    for (int j = 0; j < NT; ++j) {
        const int cur = j & 1;

        f32x4 sc[4];
#pragma unroll
        for (int nt = 0; nt < 4; ++nt) {
            const int row = nt * 16 + l15;
            bf16x8 kf0 = *(const bf16x8*)&Klds[cur][row * 64 +
                                                    ATT_SLOT(quad, row)];
            bf16x8 kf1 = *(const bf16x8*)&Klds[cur][row * 64 +
                                                    ATT_SLOT(quad + 4, row)];
            sc[nt] = {0.f, 0.f, 0.f, 0.f};
            sc[nt] = __builtin_amdgcn_mfma_f32_16x16x32_bf16(qf0, kf0, sc[nt], 0, 0, 0);
            sc[nt] = __builtin_amdgcn_mfma_f32_16x16x32_bf16(qf1, kf1, sc[nt], 0, 0, 0);
        }

        if (j >= NT - 2) {
            const int qrow_base = q0 + w * 16 + quad * 4;
#pragma unroll
            for (int nt = 0; nt < 4; ++nt) {
                const int kcol = j * 64 + nt * 16 + l15;
#pragma unroll
                for (int r = 0; r < 4; ++r)
                    if (kcol > qrow_base + r) sc[nt][r] = -1e30f;
            }
        }

#pragma unroll
        for (int nt = 0; nt < 4; ++nt)
#pragma unroll
            for (int r = 0; r < 4; ++r)
                sc[nt][r] = __expf(sc[nt][r]);

#pragma unroll
        for (int nt = 0; nt < 4; ++nt)
#pragma unroll
            for (int r = 0; r < 4; ++r)
                Plds[w][quad * 4 + r][nt * 16 + l15] = (__bf16)sc[nt][r];
        asm volatile("s_waitcnt lgkmcnt(0)" ::: "memory");

        bf16x8 pf0 = *(const bf16x8*)&Plds[w][l15][quad * 8];
        bf16x8 pf1 = *(const bf16x8*)&Plds[w][l15][32 + quad * 8];

        lacc = __builtin_amdgcn_mfma_f32_16x16x32_bf16(pf0, ones, lacc, 0, 0, 0);
        lacc = __builtin_amdgcn_mfma_f32_16x16x32_bf16(pf1, ones, lacc, 0, 0, 0);

#pragma unroll
        for (int nd = 0; nd < 4; ++nd) {
            const int row = nd * 16 + l15;
            bf16x8 vf0 = *(const bf16x8*)&Vlds[cur][row * 64 +
                                                    ATT_SLOT(quad, row)];
            bf16x8 vf1 = *(const bf16x8*)&Vlds[cur][row * 64 +
                                                    ATT_SLOT(quad + 4, row)];
            o[nd] = __builtin_amdgcn_mfma_f32_16x16x32_bf16(pf0, vf0, o[nd], 0, 0, 0);
            o[nd] = __builtin_amdgcn_mfma_f32_16x16x32_bf16(pf1, vf1, o[nd], 0, 0, 0);
        }

        __syncthreads();
        if (j + 2 < NT) {
            ASYNC_LOAD16(gK + (size_t)(j + 2) * 64 * DMODEL, &Klds[cur][t * 8]);
            ASYNC_LOAD16(gV + (size_t)(j + 2) * 64, &Vlds[cur][t * 8]);
        }
        if (j + 1 < NT) {
            if (j + 2 < NT)
                asm volatile("s_waitcnt vmcnt(2)" ::: "memory");
            else
                asm volatile("s_waitcnt vmcnt(0)" ::: "memory");
            __builtin_amdgcn_s_barrier();
        }
    }

    float rinv[4];
#pragma unroll
    for (int r = 0; r < 4; ++r) rinv[r] = 1.0f / lacc[r];
#pragma unroll
    for (int nd = 0; nd < 4; ++nd) {
#pragma unroll
        for (int r = 0; r < 4; ++r) {
            const int row = q0 + w * 16 + quad * 4 + r;
            attnbuf[(size_t)(b * 1024 + row) * DMODEL + h * 64 + nd * 16 + l15] =
                (__bf16)(o[nd][r] * rinv[r]);
        }
    }
}

extern "C" void kernel_launch(void* const* d_in, const int* in_sizes, int n_in,
                              void* d_out, int out_size, void* d_ws, size_t ws_size,
                              hipStream_t stream) {
    const float* x     = (const float*)d_in[0];
    const int* bar     = (const int*)d_in[2];
    const int* beat    = (const int*)d_in[3];
    const float* Wq    = (const float*)d_in[4];
    const float* bq    = (const float*)d_in[5];
    const float* Wk    = (const float*)d_in[6];
    const float* bk    = (const float*)d_in[7];
    const float* Wv    = (const float*)d_in[8];
    const float* bv    = (const float*)d_in[9];
    const float* Wbar  = (const float*)d_in[10];
    const float* bbar  = (const float*)d_in[11];
    const float* Wbeat = (const float*)d_in[12];
    const float* bbeat = (const float*)d_in[13];
    const float* Wo    = (const float*)d_in[14];
    const float* bo    = (const float*)d_in[15];

    const size_t M1 = (size_t)1 << 20;
    __bf16* xb     = (__bf16*)d_ws;       // 4M
    __bf16* Wqb    = xb + 4 * M1;         // 6 x 1M weights
    __bf16* Wkb    = Wqb + M1;
    __bf16* Wvb    = Wkb + M1;
    __bf16* Wbarb  = Wvb + M1;
    __bf16* Wbeatb = Wbarb + M1;
    __bf16* Wob    = Wbeatb + M1;
    __bf16* qbuf   = Wob + M1;            // 4M
    __bf16* keff   = qbuf + 4 * M1;       // 4M
    __bf16* vt     = keff + 4 * M1;       // 4M
    __bf16* attn   = vt + 4 * M1;         // 4M
    float*  outb   = (float*)d_out;

    cvt_kernel<<<5120, 256, 0, stream>>>(x, Wq, Wk, Wv, Wbar, Wbeat, Wo, xb);

    gemm8p_kernel<<<384, 512, 0, stream>>>(
        xb, Wqb, Wkb, Wvb, Wbarb, Wbeatb,
        bq, bk, bv, bbar, bbeat, bar, beat,
        qbuf, keff, vt);

    attn_kernel<<<512, 512, 0, stream>>>(qbuf, keff, vt, attn);

    oproj_kernel<<<512, 256, 0, stream>>>(attn, Wob, bo, outb);
}

// Round 6
// 201.952 us; speedup vs baseline: 1.0860x; 1.0860x over previous
//
#include <hip/hip_runtime.h>
#include <hip/hip_bf16.h>

// B=4, S=1024, D=1024, H=16, HD=64 — tokens M=4096, feature K=1024
// fp32 inputs -> bf16 convert pass -> all GEMMs/attention in bf16 MFMA
// (fp32 accumulate) -> fp32 output.
// ROUND 6: revert gemm8p K-loop to the round-3 2-phase/3-buffer schedule
// (verified 57.5 µs; round-5's single-barrier reg-dbuf regressed to 72.5 —
// pre-barrier lgkm(0) serialized the read queue). NEW: T1 XCD-aware block
// swizzle. gemm8p FETCH was 61.4 MB vs ~20 MB unique (3x over-fetch):
// default bid%8 round-robin spreads the 32 same-weight-panel blocks over
// all 8 XCD L2s. Remap (bijective per 128-block mode group): xcd=grp&7,
// n=xcd>>1, m=(grp>>3)*2|(xcd&1) — each XCD pair owns one n-group so
// weight panels stay L2-resident. oproj similarly (same-m per XCD).
// attn already XCD-local per (b,h) (id&7==bh&7) — unchanged from round 4.

typedef __bf16 bf16x8 __attribute__((ext_vector_type(8)));
typedef __bf16 bf16x4 __attribute__((ext_vector_type(4)));
typedef float  f32x4  __attribute__((ext_vector_type(4)));

#define DMODEL 1024

#define ASYNC_LOAD16(gp, lp)                                                  \
    __builtin_amdgcn_global_load_lds(                                         \
        (const __attribute__((address_space(1))) unsigned int*)(gp),          \
        (__attribute__((address_space(3))) unsigned int*)(lp), 16, 0, 0)

// ---------------------------------------------------------------------------
// fp32 -> bf16 conversion: x (4M) + 6 weights (1M each); Wbar pre-scaled by
// 0.2 and Wbeat by 0.1 (folds the score-bias scales into the GEMM).
// ---------------------------------------------------------------------------
__global__ __launch_bounds__(256) void cvt_kernel(
    const float* __restrict__ x,
    const float* __restrict__ Wq, const float* __restrict__ Wk,
    const float* __restrict__ Wv, const float* __restrict__ Wbar,
    const float* __restrict__ Wbeat, const float* __restrict__ Wo,
    __bf16* __restrict__ dst)
{
    const int g = blockIdx.x * 256 + threadIdx.x;
    const size_t e = (size_t)g * 8;
    const int seg = (int)(e >> 20);
    const float* src; size_t off; float s = 1.0f;
    if (seg < 4)       { src = x;     off = e; }
    else if (seg == 4) { src = Wq;    off = e - ((size_t)4 << 20); }
    else if (seg == 5) { src = Wk;    off = e - ((size_t)5 << 20); }
    else if (seg == 6) { src = Wv;    off = e - ((size_t)6 << 20); }
    else if (seg == 7) { src = Wbar;  off = e - ((size_t)7 << 20); s = 0.2f; }
    else if (seg == 8) { src = Wbeat; off = e - ((size_t)8 << 20); s = 0.1f; }
    else               { src = Wo;    off = e - ((size_t)9 << 20); }
    const float4 a = *(const float4*)&src[off];
    const float4 b = *(const float4*)&src[off + 4];
    bf16x8 v;
    v[0] = (__bf16)(a.x * s); v[1] = (__bf16)(a.y * s);
    v[2] = (__bf16)(a.z * s); v[3] = (__bf16)(a.w * s);
    v[4] = (__bf16)(b.x * s); v[5] = (__bf16)(b.y * s);
    v[6] = (__bf16)(b.z * s); v[7] = (__bf16)(b.w * s);
    *(bf16x8*)&dst[e] = v;
}

// ---------------------------------------------------------------------------
// 2-phase / 3-buffer GEMM (round-3 schedule, verified): BM=128, BN=256,
// BK=64, 512 threads = 8 waves (2M x 4N), wave tile 64x64 (acc 4x4).
// LDS: A 3x[128][64] + B 3x[256][64] = 144KB, T2 swizzle
// byte^=((row&7)<<4) on source + read (0 conflicts verified).
// Per K-tile t (read buf rc=t%3, stage buf fc=(t+2)%3):
//   phA: 16x ds_read_b128 (all frags); stage A(t+2); barrier; lgkm(0);
//        setprio; 16 MFMA (nh=0); setprio.
//   phB: stage B(t+2); vmcnt(6) [2-K-tile issue-to-wait]; barrier;
//        lgkm(0); 16 MFMA (nh=1).  Drain vmcnt(0) at kt==nkt-2.
// T1 block map: per 128-block mode group, xcd=grp&7, n0=(xcd>>1)<<8,
// m0=(((grp>>3)<<1)|(xcd&1))<<7 — same weight panel per XCD pair.
// ---------------------------------------------------------------------------

#define SWZ_COL(r_, ks_) \
    (((((ks_) * 64) + quad * 16) ^ (((r_) & 7) << 4)) >> 1)

#define READ_ALL(c_)                                                          \
    do {                                                                      \
        _Pragma("unroll") for (int mh = 0; mh < 2; ++mh)                      \
        _Pragma("unroll") for (int mi = 0; mi < 2; ++mi) {                    \
            const int r_ = ((w >> 2) << 5) + mh * 64 + mi * 16 + l15;         \
            _Pragma("unroll") for (int ks = 0; ks < 2; ++ks)                  \
                af[mh][mi][ks] = *(const bf16x8*)&Alds[(c_) * 8192 +          \
                                        r_ * 64 + SWZ_COL(r_, ks)];           \
        }                                                                     \
        _Pragma("unroll") for (int nh = 0; nh < 2; ++nh)                      \
        _Pragma("unroll") for (int nj = 0; nj < 2; ++nj) {                    \
            const int r_ = ((w & 3) << 5) + nh * 128 + nj * 16 + l15;         \
            _Pragma("unroll") for (int ks = 0; ks < 2; ++ks)                  \
                bfr[nh][nj][ks] = *(const bf16x8*)&Blds[(c_) * 16384 +        \
                                        r_ * 64 + SWZ_COL(r_, ks)];           \
        }                                                                     \
    } while (0)

#define STAGE_A1(bufn_, h_, kt_)                                              \
    do {                                                                      \
        const int tm_ = (kt_) >> 4;                                           \
        const int k0_ = ((kt_) & 15) << 6;                                    \
        const __bf16* ap_ = (tm_ == 0) ? aA0##h_ : (tm_ == 1) ? aA1##h_       \
                                                              : aA2##h_;      \
        ASYNC_LOAD16(ap_ + k0_,                                               \
                     &Alds[(bufn_) * 8192 + (h_) * 4096 + w * 512]);          \
    } while (0)

#define STAGE_B2(bufn_, h_, kt_)                                              \
    do {                                                                      \
        const int tm_ = (kt_) >> 4;                                           \
        const int k0_ = ((kt_) & 15) << 6;                                    \
        const __bf16* wp_ = (tm_ == 0) ? W0 : (tm_ == 1) ? W1 : W2;           \
        ASYNC_LOAD16(wp_ + bro##h_##0 + k0_,                                  \
                     &Blds[(bufn_) * 16384 + (h_) * 8192 + w * 512]);         \
        ASYNC_LOAD16(wp_ + bro##h_##1 + k0_,                                  \
                     &Blds[(bufn_) * 16384 + (h_) * 8192 + 4096 + w * 512]);  \
    } while (0)

#define PHASE_BAR1()                                                          \
    do {                                                                      \
        __builtin_amdgcn_s_barrier();                                         \
        asm volatile("s_waitcnt lgkmcnt(0)" ::: "memory");                    \
    } while (0)

#define MFMA16(nh_)                                                           \
    do {                                                                      \
        __builtin_amdgcn_s_setprio(1);                                        \
        _Pragma("unroll") for (int mh = 0; mh < 2; ++mh)                      \
        _Pragma("unroll") for (int mi = 0; mi < 2; ++mi)                      \
        _Pragma("unroll") for (int nj = 0; nj < 2; ++nj)                      \
        _Pragma("unroll") for (int ks = 0; ks < 2; ++ks) {                    \
            acc[mh * 2 + mi][(nh_) * 2 + nj] =                                \
                __builtin_amdgcn_mfma_f32_16x16x32_bf16(                      \
                    af[mh][mi][ks], bfr[(nh_)][nj][ks],                       \
                    acc[mh * 2 + mi][(nh_) * 2 + nj], 0, 0, 0);               \
        }                                                                     \
        __builtin_amdgcn_s_setprio(0);                                        \
    } while (0)

__global__ __launch_bounds__(512, 2) void gemm8p_kernel(
    const __bf16* __restrict__ xb,
    const __bf16* __restrict__ Wqb, const __bf16* __restrict__ Wkb,
    const __bf16* __restrict__ Wvb, const __bf16* __restrict__ Wbarb,
    const __bf16* __restrict__ Wbeatb,
    const float* __restrict__ bq, const float* __restrict__ bk,
    const float* __restrict__ bv, const float* __restrict__ bbar,
    const float* __restrict__ bbeat,
    const int* __restrict__ bar_idx, const int* __restrict__ beat_idx,
    __bf16* __restrict__ qbuf, __bf16* __restrict__ keffbuf,
    __bf16* __restrict__ vtbuf)
{
    __shared__ __align__(16) __bf16 Alds[3 * 8192];    // 3 buf x [128][64]
    __shared__ __align__(16) __bf16 Blds[3 * 16384];   // 3 buf x [256][64]

    const int bid = blockIdx.x;
    int mode, grp;
    if (bid < 128)      { mode = 1; grp = bid; }        // keff first (3x work)
    else if (bid < 256) { mode = 0; grp = bid - 128; }  // q
    else                { mode = 2; grp = bid - 256; }  // v
    // T1 XCD swizzle: xcd = grp&7 (== bid%8 since group bases are %8==0).
    // Same n-column group per XCD pair -> weight panels L2-resident.
    const int xcd = grp & 7;
    const int m0 = ((((grp >> 3) << 1) | (xcd & 1))) << 7;  // 32 m-tiles
    const int n0 = (xcd >> 1) << 8;                          // 4 n-tiles
    const int nkt = (mode == 1) ? 48 : 16;

    const int t    = (int)threadIdx.x;
    const int w    = t >> 6;
    const int lane = t & 63;
    const int l15  = lane & 15;
    const int quad = lane >> 4;

    // staging: thread t stages 16B at linear LDS byte t*16 within the
    // half-tile block => row = t>>3, slot = t&7. Source col carries the
    // involution swizzle: byte ^= ((row&7)<<4).
    const int srow = t >> 3;                                    // 0..63
    const int scol = ((((t & 7) * 16) ^ (((t >> 3) & 7) << 4)) >> 1);

    const __bf16* aA00 = xb + (size_t)(m0 + srow) * DMODEL + scol;
    const __bf16* aA01 = xb + (size_t)(m0 + 64 + srow) * DMODEL + scol;
    const __bf16* aA10 = aA00; const __bf16* aA11 = aA01;
    const __bf16* aA20 = aA00; const __bf16* aA21 = aA01;
    const __bf16 *W0, *W1, *W2;
    if (mode == 0)      { W0 = W1 = W2 = Wqb; }
    else if (mode == 2) { W0 = W1 = W2 = Wvb; }
    else {
        W0 = Wkb; W1 = Wbarb; W2 = Wbeatb;
        const int bb = m0 & ~1023;                 // batch base row
        const int lr = m0 & 1023;                  // seq-local tile base
        aA10 = xb + (size_t)(bb + bar_idx[lr + srow]) * DMODEL + scol;
        aA11 = xb + (size_t)(bb + bar_idx[lr + 64 + srow]) * DMODEL + scol;
        aA20 = xb + (size_t)(bb + beat_idx[lr + srow]) * DMODEL + scol;
        aA21 = xb + (size_t)(bb + beat_idx[lr + 64 + srow]) * DMODEL + scol;
    }
    const size_t bro00 = (size_t)(n0 + srow) * DMODEL + scol;
    const size_t bro01 = (size_t)(n0 + 64 + srow) * DMODEL + scol;
    const size_t bro10 = (size_t)(n0 + 128 + srow) * DMODEL + scol;
    const size_t bro11 = (size_t)(n0 + 192 + srow) * DMODEL + scol;

    f32x4 acc[4][4];
#pragma unroll
    for (int i = 0; i < 4; ++i)
#pragma unroll
        for (int j = 0; j < 4; ++j)
            acc[i][j] = {0.f, 0.f, 0.f, 0.f};
    bf16x8 af[2][2][2], bfr[2][2][2];

    // prologue: stage tiles 0 and 1 fully; wait tile 0 (vmcnt(6)), publish.
    STAGE_A1(0, 0, 0);
    STAGE_A1(0, 1, 0);
    STAGE_B2(0, 0, 0);
    STAGE_B2(0, 1, 0);
    asm volatile("" ::: "memory");
    STAGE_A1(1, 0, 1);
    STAGE_A1(1, 1, 1);
    STAGE_B2(1, 0, 1);
    STAGE_B2(1, 1, 1);
    asm volatile("s_waitcnt vmcnt(6)" ::: "memory");
    __builtin_amdgcn_s_barrier();

    int rc = 0, fc = 2;
#pragma unroll 1
    for (int kt = 0; kt < nkt; ++kt) {
        const int kn = kt + 2;
        const bool st = (kn < nkt);

        // phA: all ds_reads of tile kt; A-stage of kt+2
        READ_ALL(rc);
        if (st) { STAGE_A1(fc, 0, kn); STAGE_A1(fc, 1, kn); }
        PHASE_BAR1();
        MFMA16(0);

        // phB: B-stage of kt+2; single counted wait; publish tile kt+1
        if (st) { STAGE_B2(fc, 0, kn); STAGE_B2(fc, 1, kn); }
        if (kt < nkt - 2)
            asm volatile("s_waitcnt vmcnt(6)" ::: "memory");
        else if (kt == nkt - 2)
            asm volatile("s_waitcnt vmcnt(0)" ::: "memory");
        PHASE_BAR1();
        MFMA16(1);

        rc = (rc == 2) ? 0 : rc + 1;
        fc = (fc == 2) ? 0 : fc + 1;
    }

    // epilogue: fp32 bias + store
#pragma unroll
    for (int an = 0; an < 4; ++an) {
        const int col = n0 + ((w & 3) << 5) + (an >> 1) * 128 +
                        (an & 1) * 16 + l15;
        float bias;
        if (mode == 0)      bias = bq[col];
        else if (mode == 1) bias = bk[col] + 0.2f * bbar[col] + 0.1f * bbeat[col];
        else                bias = bv[col];
#pragma unroll
        for (int am = 0; am < 4; ++am) {
            const int rowbase = m0 + ((w >> 2) << 5) + (am >> 1) * 64 +
                                (am & 1) * 16 + quad * 4;
            if (mode == 2) {
                const int bb = rowbase >> 10;
                const int sb2 = rowbase & 1023;
                bf16x4 vv;
#pragma unroll
                for (int r = 0; r < 4; ++r) vv[r] = (__bf16)(acc[am][an][r] + bias);
                *(bf16x4*)&vtbuf[((size_t)(bb * 1024 + col)) * 1024 + sb2] = vv;
            } else if (mode == 0) {
#pragma unroll
                for (int r = 0; r < 4; ++r)
                    qbuf[(size_t)(rowbase + r) * DMODEL + col] =
                        (__bf16)((acc[am][an][r] + bias) * 0.125f);  // attn scale
            } else {
#pragma unroll
                for (int r = 0; r < 4; ++r)
                    keffbuf[(size_t)(rowbase + r) * DMODEL + col] =
                        (__bf16)(acc[am][an][r] + bias);
            }
        }
    }
}

// ---------------------------------------------------------------------------
// out-proj: out = attn @ Wo^T + bo (fp32). 64x128 tile, grid 512 (2/CU).
// T1 XCD swizzle: same-m blocks share an XCD (attn A-panels L2-resident;
// Wo fetched once per XCD). m = xcd*8 + (k>>3), n = k&7 — bijective.
// ---------------------------------------------------------------------------
__global__ __launch_bounds__(256) void oproj_kernel(
    const __bf16* __restrict__ attnb, const __bf16* __restrict__ Wob,
    const float* __restrict__ bo, float* __restrict__ outb)
{
    const int bidx = blockIdx.x;          // 512 = 64 (m) x 8 (n)
    const int xcd = bidx & 7;
    const int kk2 = bidx >> 3;            // 0..63
    const int m0 = (((xcd << 3) | (kk2 >> 3))) << 6;   // 64 m-tiles
    const int n0 = (kk2 & 7) << 7;                     // 8 n-tiles

    __shared__ __align__(16) __bf16 Alds[64 * 32];
    __shared__ __align__(16) __bf16 Blds[128 * 32];

    const int t    = threadIdx.x;
    const int w    = t >> 6;
    const int lane = t & 63;
    const int l15  = lane & 15;
    const int quad = lane >> 4;
    const int wm   = (w >> 1) << 5;   // 2 m-waves x 2 n-waves
    const int wn   = (w & 1) << 6;
    const int srow = t >> 2;
    const int scol = ((((t & 3) * 16) ^ (((t >> 2) & 3) << 4)) >> 1);
    const int rcol = (((quad * 16) ^ ((l15 & 3) << 4)) >> 1);

    const __bf16* gA  = attnb + (size_t)(m0 + srow) * DMODEL + scol;
    const __bf16* gB0 = Wob + (size_t)(n0 + srow) * DMODEL + scol;
    const __bf16* gB1 = Wob + (size_t)(n0 + 64 + srow) * DMODEL + scol;
    __bf16* lA  = &Alds[w * 512];
    __bf16* lB0 = &Blds[w * 512];
    __bf16* lB1 = &Blds[2048 + w * 512];

    f32x4 acc[2][4];
    for (int i = 0; i < 2; ++i)
        for (int j = 0; j < 4; ++j)
            acc[i][j] = {0.f, 0.f, 0.f, 0.f};

    for (int kk = 0; kk < 32; ++kk) {
        const int k0 = kk * 32;
        ASYNC_LOAD16(gA + k0, lA);
        ASYNC_LOAD16(gB0 + k0, lB0);
        ASYNC_LOAD16(gB1 + k0, lB1);
        __syncthreads();

        bf16x8 af[2], bfr[4];
        for (int i = 0; i < 2; ++i)
            af[i] = *(const bf16x8*)&Alds[(wm + i * 16 + l15) * 32 + rcol];
        for (int j = 0; j < 4; ++j)
            bfr[j] = *(const bf16x8*)&Blds[(wn + j * 16 + l15) * 32 + rcol];

        for (int i = 0; i < 2; ++i)
            for (int j = 0; j < 4; ++j)
                acc[i][j] = __builtin_amdgcn_mfma_f32_16x16x32_bf16(
                    af[i], bfr[j], acc[i][j], 0, 0, 0);
        __syncthreads();
    }

    for (int j = 0; j < 4; ++j) {
        const int col = n0 + wn + j * 16 + l15;
        const float bias = bo[col];
        for (int i = 0; i < 2; ++i) {
            const int rowbase = m0 + wm + i * 16 + quad * 4;
            for (int r = 0; r < 4; ++r)
                outb[(size_t)(rowbase + r) * DMODEL + col] = acc[i][j][r] + bias;
        }
    }
}

// ---------------------------------------------------------------------------
// flash attention (unchanged from round 4): 512 blocks x 512 threads,
// QBLK=128, K/V 64-row tiles double-buffered via global_load_lds + T2
// swizzle, one-tile-ahead prefetch with counted vmcnt(2), complement
// qt-pairing. Shift-free softmax, ones-MFMA rowsum. Same-(b,h) blocks
// already land on one XCD (id&7 == bh&7) — K/V L2-local by construction.
// ---------------------------------------------------------------------------
#define ATT_SLOT(q_, r_) ((((q_) ^ ((r_) & 7))) * 8)

__global__ __launch_bounds__(512) void attn_kernel(
    const __bf16* __restrict__ qbuf, const __bf16* __restrict__ keffbuf,
    const __bf16* __restrict__ vtbuf, __bf16* __restrict__ attnbuf)
{
    const int id = blockIdx.x;            // 512 = 64 bh x 8 qr
    const int bh = id & 63;
    const int b  = bh >> 4;
    const int h  = bh & 15;
    const int qr = id >> 6;
    const int qt = (qr < 4) ? qr : 11 - qr;   // complement pairing: 18 it/CU
    const int q0 = qt << 7;                   // 128 q-rows per block
    const int NT = 2 * qt + 2;                // causal K/V tiles of 64

    __shared__ __align__(16) __bf16 Klds[2][64 * 64];
    __shared__ __align__(16) __bf16 Vlds[2][64 * 64];
    __shared__ __align__(16) __bf16 Plds[8][16][72];

    const int t    = (int)threadIdx.x;
    const int w    = t >> 6;
    const int lane = t & 63;
    const int l15  = lane & 15;
    const int quad = lane >> 4;

    const int srow = t >> 3;                           // 0..63
    const int scol = ((t & 7) ^ (srow & 7)) * 8;       // elements, [0,64)

    const __bf16* gK = keffbuf + (size_t)(b * 1024 + srow) * DMODEL +
                       h * 64 + scol;                  // + j*64*DMODEL
    const __bf16* gV = vtbuf + (size_t)(b * 1024 + h * 64 + srow) * 1024 +
                       scol;                           // + j*64

    const __bf16* qbase =
        qbuf + (size_t)(b * 1024 + q0 + w * 16 + l15) * DMODEL + h * 64;
    bf16x8 qf0 = *(const bf16x8*)&qbase[quad * 8];
    bf16x8 qf1 = *(const bf16x8*)&qbase[32 + quad * 8];

    bf16x8 ones;
#pragma unroll
    for (int i = 0; i < 8; ++i) ones[i] = (__bf16)1.0f;

    f32x4 o[4];
#pragma unroll
    for (int i = 0; i < 4; ++i) o[i] = {0.f, 0.f, 0.f, 0.f};
    f32x4 lacc = {0.f, 0.f, 0.f, 0.f};

    ASYNC_LOAD16(gK, &Klds[0][t * 8]);
    ASYNC_LOAD16(gV, &Vlds[0][t * 8]);
    asm volatile("" ::: "memory");
    ASYNC_LOAD16(gK + (size_t)64 * DMODEL, &Klds[1][t * 8]);
    ASYNC_LOAD16(gV + 64, &Vlds[1][t * 8]);
    asm volatile("s_waitcnt vmcnt(2)" ::: "memory");
    __builtin_amdgcn_s_barrier();

#pragma unroll 1
    for (int j = 0; j < NT; ++j) {
        const int cur = j & 1;

        f32x4 sc[4];
#pragma unroll
        for (int nt = 0; nt < 4; ++nt) {
            const int row = nt * 16 + l15;
            bf16x8 kf0 = *(const bf16x8*)&Klds[cur][row * 64 +
                                                    ATT_SLOT(quad, row)];
            bf16x8 kf1 = *(const bf16x8*)&Klds[cur][row * 64 +
                                                    ATT_SLOT(quad + 4, row)];
            sc[nt] = {0.f, 0.f, 0.f, 0.f};
            sc[nt] = __builtin_amdgcn_mfma_f32_16x16x32_bf16(qf0, kf0, sc[nt], 0, 0, 0);
            sc[nt] = __builtin_amdgcn_mfma_f32_16x16x32_bf16(qf1, kf1, sc[nt], 0, 0, 0);
        }

        if (j >= NT - 2) {
            const int qrow_base = q0 + w * 16 + quad * 4;
#pragma unroll
            for (int nt = 0; nt < 4; ++nt) {
                const int kcol = j * 64 + nt * 16 + l15;
#pragma unroll
                for (int r = 0; r < 4; ++r)
                    if (kcol > qrow_base + r) sc[nt][r] = -1e30f;
            }
        }

#pragma unroll
        for (int nt = 0; nt < 4; ++nt)
#pragma unroll
            for (int r = 0; r < 4; ++r)
                sc[nt][r] = __expf(sc[nt][r]);

#pragma unroll
        for (int nt = 0; nt < 4; ++nt)
#pragma unroll
            for (int r = 0; r < 4; ++r)
                Plds[w][quad * 4 + r][nt * 16 + l15] = (__bf16)sc[nt][r];
        asm volatile("s_waitcnt lgkmcnt(0)" ::: "memory");

        bf16x8 pf0 = *(const bf16x8*)&Plds[w][l15][quad * 8];
        bf16x8 pf1 = *(const bf16x8*)&Plds[w][l15][32 + quad * 8];

        lacc = __builtin_amdgcn_mfma_f32_16x16x32_bf16(pf0, ones, lacc, 0, 0, 0);
        lacc = __builtin_amdgcn_mfma_f32_16x16x32_bf16(pf1, ones, lacc, 0, 0, 0);

#pragma unroll
        for (int nd = 0; nd < 4; ++nd) {
            const int row = nd * 16 + l15;
            bf16x8 vf0 = *(const bf16x8*)&Vlds[cur][row * 64 +
                                                    ATT_SLOT(quad, row)];
            bf16x8 vf1 = *(const bf16x8*)&Vlds[cur][row * 64 +
                                                    ATT_SLOT(quad + 4, row)];
            o[nd] = __builtin_amdgcn_mfma_f32_16x16x32_bf16(pf0, vf0, o[nd], 0, 0, 0);
            o[nd] = __builtin_amdgcn_mfma_f32_16x16x32_bf16(pf1, vf1, o[nd], 0, 0, 0);
        }

        __syncthreads();
        if (j + 2 < NT) {
            ASYNC_LOAD16(gK + (size_t)(j + 2) * 64 * DMODEL, &Klds[cur][t * 8]);
            ASYNC_LOAD16(gV + (size_t)(j + 2) * 64, &Vlds[cur][t * 8]);
        }
        if (j + 1 < NT) {
            if (j + 2 < NT)
                asm volatile("s_waitcnt vmcnt(2)" ::: "memory");
            else
                asm volatile("s_waitcnt vmcnt(0)" ::: "memory");
            __builtin_amdgcn_s_barrier();
        }
    }

    float rinv[4];
#pragma unroll
    for (int r = 0; r < 4; ++r) rinv[r] = 1.0f / lacc[r];
#pragma unroll
    for (int nd = 0; nd < 4; ++nd) {
#pragma unroll
        for (int r = 0; r < 4; ++r) {
            const int row = q0 + w * 16 + quad * 4 + r;
            attnbuf[(size_t)(b * 1024 + row) * DMODEL + h * 64 + nd * 16 + l15] =
                (__bf16)(o[nd][r] * rinv[r]);
        }
    }
}

extern "C" void kernel_launch(void* const* d_in, const int* in_sizes, int n_in,
                              void* d_out, int out_size, void* d_ws, size_t ws_size,
                              hipStream_t stream) {
    const float* x     = (const float*)d_in[0];
    const int* bar     = (const int*)d_in[2];
    const int* beat    = (const int*)d_in[3];
    const float* Wq    = (const float*)d_in[4];
    const float* bq    = (const float*)d_in[5];
    const float* Wk    = (const float*)d_in[6];
    const float* bk    = (const float*)d_in[7];
    const float* Wv    = (const float*)d_in[8];
    const float* bv    = (const float*)d_in[9];
    const float* Wbar  = (const float*)d_in[10];
    const float* bbar  = (const float*)d_in[11];
    const float* Wbeat = (const float*)d_in[12];
    const float* bbeat = (const float*)d_in[13];
    const float* Wo    = (const float*)d_in[14];
    const float* bo    = (const float*)d_in[15];

    const size_t M1 = (size_t)1 << 20;
    __bf16* xb     = (__bf16*)d_ws;       // 4M
    __bf16* Wqb    = xb + 4 * M1;         // 6 x 1M weights
    __bf16* Wkb    = Wqb + M1;
    __bf16* Wvb    = Wkb + M1;
    __bf16* Wbarb  = Wvb + M1;
    __bf16* Wbeatb = Wbarb + M1;
    __bf16* Wob    = Wbeatb + M1;
    __bf16* qbuf   = Wob + M1;            // 4M
    __bf16* keff   = qbuf + 4 * M1;       // 4M
    __bf16* vt     = keff + 4 * M1;       // 4M
    __bf16* attn   = vt + 4 * M1;         // 4M
    float*  outb   = (float*)d_out;

    cvt_kernel<<<5120, 256, 0, stream>>>(x, Wq, Wk, Wv, Wbar, Wbeat, Wo, xb);

    gemm8p_kernel<<<384, 512, 0, stream>>>(
        xb, Wqb, Wkb, Wvb, Wbarb, Wbeatb,
        bq, bk, bv, bbar, bbeat, bar, beat,
        qbuf, keff, vt);

    attn_kernel<<<512, 512, 0, stream>>>(qbuf, keff, vt, attn);

    oproj_kernel<<<512, 256, 0, stream>>>(attn, Wob, bo, outb);
}